// Round 8
// baseline (173.214 us; speedup 1.0000x reference)
//
#include <hip/hip_runtime.h>
#include <math.h>

// Problem constants
#define B 64
#define S 2048
#define H 1024
#define E 512
#define V 32000
#define G4 4096        // 4*H
#define KX 1536        // E+H
#define KC 2560        // E+H+H
#define NVT 500        // number of v-tiles in logits GEMM (V/64)

typedef __attribute__((ext_vector_type(8))) short short8v;
typedef __attribute__((ext_vector_type(4))) float f32x4;

__device__ __forceinline__ ushort f2bf(float f) {
    union { float f; unsigned u; } v; v.f = f;
    unsigned r = v.u + 0x7FFFu + ((v.u >> 16) & 1u);
    return (ushort)(r >> 16);
}

__device__ __forceinline__ float4 ntload4(const float* p) {
    f32x4 v = __builtin_nontemporal_load((const f32x4*)p);
    return make_float4(v[0], v[1], v[2], v[3]);
}

__device__ __forceinline__ void packbf(const float4& a, const float4& b, short8v& o) {
    o[0] = (short)f2bf(a.x); o[1] = (short)f2bf(a.y);
    o[2] = (short)f2bf(a.z); o[3] = (short)f2bf(a.w);
    o[4] = (short)f2bf(b.x); o[5] = (short)f2bf(b.y);
    o[6] = (short)f2bf(b.z); o[7] = (short)f2bf(b.w);
}

// ---------------- K1: fused flash attention over enc (single enc pass) ------
// 1024 blocks: b = blk>>4, cpair = blk&15 -> s-chunks {2*cpair, 2*cpair+1}.
// Flat 32-row loop per wave with depth-2 prefetch.
__global__ __launch_bounds__(256) void fused_attn_kernel(const float* __restrict__ enc,
                                                         const float* __restrict__ attn_W,
                                                         const float* __restrict__ attn_b,
                                                         const float* __restrict__ prev_h,
                                                         float* __restrict__ scores,
                                                         float* __restrict__ cpart,
                                                         float* __restrict__ mlc) {
    __shared__ float red[256];
    __shared__ float mw[4], lw[4];
    __shared__ float cbuf[4][1024];
    int t = threadIdx.x;
    int lane = t & 63, wid = t >> 6;
    int b = blockIdx.x >> 4, cpair = blockIdx.x & 15;

    // inline hwh[b] = dot(prev_h[b,:], attn_W[0:H])
    {
        float4 p = *(const float4*)(prev_h + b * H + t * 4);
        float4 w = *(const float4*)(attn_W + t * 4);
        red[t] = p.x * w.x + p.y * w.y + p.z * w.z + p.w * w.w;
        __syncthreads();
        for (int s2 = 128; s2; s2 >>= 1) {
            if (t < s2) red[t] += red[t + s2];
            __syncthreads();
        }
    }
    float cst = red[0] + attn_b[0];

    const float* We = attn_W + H;
    float4 we4[4];
#pragma unroll
    for (int c = 0; c < 4; ++c) we4[c] = *(const float4*)(We + c * 256 + lane * 4);

    float m = -INFINITY, l = 0.f;
    float4 ctx4[4] = {{0,0,0,0},{0,0,0,0},{0,0,0,0},{0,0,0,0}};

    // row r in [0,32): s = cpair*128 + (r>>4)*64 + wid*16 + (r&15)
    const float* base = enc + (size_t)(cpair * 128 + wid * 16) * (B * H) + b * H + lane * 4;
#define ROWP(r) (base + (size_t)((((r) >> 4) << 6) + ((r) & 15)) * (B * H))
    float4 pa[4], pb[4];
#pragma unroll
    for (int c = 0; c < 4; ++c) pa[c] = ntload4(ROWP(0) + c * 256);
#pragma unroll
    for (int c = 0; c < 4; ++c) pb[c] = ntload4(ROWP(1) + c * 256);

    for (int r = 0; r < 32; ++r) {
        float4 cur[4];
#pragma unroll
        for (int c = 0; c < 4; ++c) cur[c] = pa[c];
#pragma unroll
        for (int c = 0; c < 4; ++c) pa[c] = pb[c];
        if (r + 2 < 32) {
            const float* np = ROWP(r + 2);
#pragma unroll
            for (int c = 0; c < 4; ++c) pb[c] = ntload4(np + c * 256);
        }
        float acc = 0.f;
#pragma unroll
        for (int c = 0; c < 4; ++c)
            acc += cur[c].x * we4[c].x + cur[c].y * we4[c].y +
                   cur[c].z * we4[c].z + cur[c].w * we4[c].w;
#pragma unroll
        for (int x = 32; x; x >>= 1) acc += __shfl_xor(acc, x);
        float score = acc + cst;
        if (lane == 0) {
            int s = cpair * 128 + ((r >> 4) << 6) + wid * 16 + (r & 15);
            scores[b * S + s] = score;
        }
        float nm = fmaxf(m, score);
        float sc = expf(m - nm);
        float w = expf(score - nm);
        l = l * sc + w;
        m = nm;
#pragma unroll
        for (int c = 0; c < 4; ++c) {
            ctx4[c].x = ctx4[c].x * sc + w * cur[c].x;
            ctx4[c].y = ctx4[c].y * sc + w * cur[c].y;
            ctx4[c].z = ctx4[c].z * sc + w * cur[c].z;
            ctx4[c].w = ctx4[c].w * sc + w * cur[c].w;
        }
    }
#undef ROWP

    if (lane == 0) { mw[wid] = m; lw[wid] = l; }
    __syncthreads();
    float M = fmaxf(fmaxf(mw[0], mw[1]), fmaxf(mw[2], mw[3]));
    float L = lw[0] * expf(mw[0] - M) + lw[1] * expf(mw[1] - M) +
              lw[2] * expf(mw[2] - M) + lw[3] * expf(mw[3] - M);
    float msc = expf(m - M);
#pragma unroll
    for (int c = 0; c < 4; ++c) {
        float4 v = ctx4[c];
        v.x *= msc; v.y *= msc; v.z *= msc; v.w *= msc;
        *(float4*)&cbuf[wid][c * 256 + lane * 4] = v;
    }
    __syncthreads();
    if (wid == 0) {
#pragma unroll
        for (int c = 0; c < 4; ++c) {
            int h = c * 256 + lane * 4;
            float4 a0 = *(float4*)&cbuf[0][h];
            float4 a1 = *(float4*)&cbuf[1][h];
            float4 a2 = *(float4*)&cbuf[2][h];
            float4 a3 = *(float4*)&cbuf[3][h];
            float4 s4 = make_float4(a0.x + a1.x + a2.x + a3.x,
                                    a0.y + a1.y + a2.y + a3.y,
                                    a0.z + a1.z + a2.z + a3.z,
                                    a0.w + a1.w + a2.w + a3.w);
            *(float4*)(cpart + (size_t)(cpair * B + b) * H + h) = s4;
        }
    }
    if (t == 0) {
        mlc[(b * 16 + cpair) * 2] = M;
        mlc[(b * 16 + cpair) * 2 + 1] = L;
    }
}

// ---------------- K2: merge partials -> xb(bf16) context + weights + fill ---
__global__ __launch_bounds__(256) void attn_reduce_kernel(const float* __restrict__ cpart,
                                                          const float* __restrict__ mlc,
                                                          const float* __restrict__ scores,
                                                          const int* __restrict__ ib,
                                                          const float* __restrict__ emb_W,
                                                          const float* __restrict__ prev_h,
                                                          ushort* __restrict__ xb,
                                                          float* __restrict__ attn) {
    __shared__ float Ms[16], Ls[16], Es[16];
    int blk = blockIdx.x;
    int b = blk >> 2, q = blk & 3;
    int t = threadIdx.x;
    if (t < 16) {
        Ms[t] = mlc[(b * 16 + t) * 2];
        Ls[t] = mlc[(b * 16 + t) * 2 + 1];
    }
    __syncthreads();
    float Mg = -INFINITY;
#pragma unroll
    for (int c = 0; c < 16; ++c) Mg = fmaxf(Mg, Ms[c]);
    if (t < 16) Es[t] = expf(Ms[t] - Mg);
    __syncthreads();
    float Lg = 0.f;
#pragma unroll
    for (int c = 0; c < 16; ++c) Lg += Ls[c] * Es[c];
    float inv = 1.f / Lg;
    int h = q * 256 + t;
    float acc = 0.f;
#pragma unroll 4
    for (int c = 0; c < 16; ++c)
        acc += Es[c] * cpart[(size_t)(c * B + b) * H + h];
    xb[(size_t)b * KC + E + h] = f2bf(acc * inv);
#pragma unroll
    for (int i = 0; i < 2; ++i) {
        int s = q * 512 + i * 256 + t;
        attn[b * S + s] = expf(scores[b * S + s] - Mg) * inv;
    }
#pragma unroll
    for (int i = 0; i < 2; ++i) {
        int j = q * 384 + i * 256 + t;
        if (i == 1 && t >= 128) break;
        if (j < E) xb[(size_t)b * KC + j] = f2bf(emb_W[(size_t)ib[b] * E + j]);
        else       xb[(size_t)b * KC + KX + (j - E)] = f2bf(prev_h[b * H + (j - E)]);
    }
}

// ---------------- K3: gates GEMM via bf16 MFMA (T14 pipelined staging) ------
__global__ __launch_bounds__(256) void gates_mfma(const float* __restrict__ W_ih,
                                                  const float* __restrict__ W_hh,
                                                  const ushort* __restrict__ xb,
                                                  float* __restrict__ gpart) {
    __shared__ ushort Wt[64 * 64];
    __shared__ ushort Bt[64 * 64];
    int t = threadIdx.x;
    int lane = t & 63, wid = t >> 6;
    int rtile = blockIdx.x >> 3, ks = blockIdx.x & 7;
    int r0 = rtile * 64;

    int srow = t >> 2;
    int sq = t & 3;

    f32x4 acc[4] = {{0.f,0.f,0.f,0.f},{0.f,0.f,0.f,0.f},{0.f,0.f,0.f,0.f},{0.f,0.f,0.f,0.f}};

    int r = lane & 15, g = lane >> 4;
    int arow = wid * 16 + r;
    int aswz = (arow & 7) << 4;
    unsigned abase = arow * 128;

    unsigned rb = srow * 128;
    unsigned sw = (srow & 7) << 4;

#define GW_PTR(kt) ({ int kb_ = ks * 320 + (kt) * 64;                                   \
    (kb_ < KX) ? (W_ih + (size_t)(r0 + srow) * KX + kb_ + sq * 16)                      \
               : (W_hh + (size_t)(r0 + srow) * H + (kb_ - KX) + sq * 16); })

    float4 f0, f1, f2, f3; uint4 h0, h1;
    {
        const float* src = GW_PTR(0);
        f0 = ntload4(src + 0); f1 = ntload4(src + 4);
        f2 = ntload4(src + 8); f3 = ntload4(src + 12);
        const ushort* hs = xb + (size_t)srow * KC + ks * 320 + sq * 16;
        h0 = *(const uint4*)(hs); h1 = *(const uint4*)(hs + 8);
    }

    for (int kt = 0; kt < 5; ++kt) {
        short8v w0, w1;
        packbf(f0, f1, w0); packbf(f2, f3, w1);
        __syncthreads();
        *(short8v*)((char*)Wt + rb + ((sq * 32 + 0) ^ sw))  = w0;
        *(short8v*)((char*)Wt + rb + ((sq * 32 + 16) ^ sw)) = w1;
        *(uint4*)((char*)Bt + rb + ((sq * 32 + 0) ^ sw))  = h0;
        *(uint4*)((char*)Bt + rb + ((sq * 32 + 16) ^ sw)) = h1;
        __syncthreads();
        if (kt < 4) {
            const float* src = GW_PTR(kt + 1);
            f0 = ntload4(src + 0); f1 = ntload4(src + 4);
            f2 = ntload4(src + 8); f3 = ntload4(src + 12);
            const ushort* hs = xb + (size_t)srow * KC + ks * 320 + (kt + 1) * 64 + sq * 16;
            h0 = *(const uint4*)(hs); h1 = *(const uint4*)(hs + 8);
        }
#pragma unroll
        for (int kk = 0; kk < 2; ++kk) {
            unsigned koff = kk * 64 + g * 16;
            short8v a = *(short8v*)((char*)Wt + abase + (koff ^ aswz));
#pragma unroll
            for (int bt = 0; bt < 4; ++bt) {
                int brow = bt * 16 + r;
                short8v bb = *(short8v*)((char*)Bt + brow * 128 + (koff ^ ((brow & 7) << 4)));
                acc[bt] = __builtin_amdgcn_mfma_f32_16x16x32_bf16(a, bb, acc[bt], 0, 0, 0);
            }
        }
    }
#undef GW_PTR
#pragma unroll
    for (int bt = 0; bt < 4; ++bt) {
        int bcol = bt * 16 + r;
#pragma unroll
        for (int j = 0; j < 4; ++j) {
            int rg = r0 + wid * 16 + g * 4 + j;
            gpart[(size_t)ks * (G4 * B) + (size_t)rg * B + bcol] = acc[bt][j];
        }
    }
}

// ---------------- K4: LSTM elementwise (8 partials, emits bf16 hb[b][k]) ----
__global__ __launch_bounds__(256) void lstm_kernel(const float* __restrict__ gpart,
                                                   const float* __restrict__ b_ih,
                                                   const float* __restrict__ b_hh,
                                                   const float* __restrict__ prev_c,
                                                   float* __restrict__ hidden_out,
                                                   float* __restrict__ cell_out,
                                                   ushort* __restrict__ hb) {
    int t = blockIdx.x * 256 + threadIdx.x;  // 65536
    int b = t & 63, h = t >> 6;
    float g[4];
#pragma unroll
    for (int q = 0; q < 4; ++q) {
        int r = h + q * H;
        float a = b_ih[r] + b_hh[r];
#pragma unroll
        for (int ks = 0; ks < 8; ++ks) a += gpart[(size_t)ks * (G4 * B) + r * B + b];
        g[q] = a;
    }
    float ig = 1.f / (1.f + expf(-g[0]));
    float fg = 1.f / (1.f + expf(-g[1]));
    float gg = tanhf(g[2]);
    float og = 1.f / (1.f + expf(-g[3]));
    float c = fg * prev_c[b * H + h] + ig * gg;
    float hd = og * tanhf(c);
    cell_out[b * H + h] = c;
    hidden_out[b * H + h] = hd;
    hb[b * H + h] = f2bf(hd);
}

// ---------------- K5: logits via bf16 MFMA (T14 pipelined) + partial LSE ----
__global__ __launch_bounds__(256) void logits_mfma(const float* __restrict__ W,
                                                   const float* __restrict__ ob,
                                                   const ushort* __restrict__ hb,
                                                   float* __restrict__ outl,
                                                   float* __restrict__ lsp) {
    __shared__ ushort Wt[64 * 64];
    __shared__ ushort Bt[64 * 64];
    __shared__ float  Ct[64][68];
    int t = threadIdx.x;
    int lane = t & 63, wid = t >> 6;
    int v0 = blockIdx.x * 64;

    int srow = t >> 2;
    int sq = t & 3;

    f32x4 acc[4] = {{0.f,0.f,0.f,0.f},{0.f,0.f,0.f,0.f},{0.f,0.f,0.f,0.f},{0.f,0.f,0.f,0.f}};

    int r = lane & 15, g = lane >> 4;
    int arow = wid * 16 + r;
    int aswz = (arow & 7) << 4;
    unsigned abase = arow * 128;

    unsigned rb = srow * 128;
    unsigned sw = (srow & 7) << 4;

    const float* wrow = W + (size_t)(v0 + srow) * H + sq * 16;
    const ushort* hrow = hb + (size_t)srow * H + sq * 16;

    float4 f0, f1, f2, f3; uint4 h0, h1;
    f0 = ntload4(wrow + 0); f1 = ntload4(wrow + 4);
    f2 = ntload4(wrow + 8); f3 = ntload4(wrow + 12);
    h0 = *(const uint4*)(hrow); h1 = *(const uint4*)(hrow + 8);

    for (int kt = 0; kt < 16; ++kt) {
        short8v w0, w1;
        packbf(f0, f1, w0); packbf(f2, f3, w1);
        __syncthreads();
        *(short8v*)((char*)Wt + rb + ((sq * 32 + 0) ^ sw))  = w0;
        *(short8v*)((char*)Wt + rb + ((sq * 32 + 16) ^ sw)) = w1;
        *(uint4*)((char*)Bt + rb + ((sq * 32 + 0) ^ sw))  = h0;
        *(uint4*)((char*)Bt + rb + ((sq * 32 + 16) ^ sw)) = h1;
        __syncthreads();
        if (kt < 15) {
            const float* src = wrow + (kt + 1) * 64;
            f0 = ntload4(src + 0); f1 = ntload4(src + 4);
            f2 = ntload4(src + 8); f3 = ntload4(src + 12);
            const ushort* hs = hrow + (kt + 1) * 64;
            h0 = *(const uint4*)(hs); h1 = *(const uint4*)(hs + 8);
        }
#pragma unroll
        for (int kk = 0; kk < 2; ++kk) {
            unsigned koff = kk * 64 + g * 16;
            short8v a = *(short8v*)((char*)Wt + abase + (koff ^ aswz));
#pragma unroll
            for (int bt = 0; bt < 4; ++bt) {
                int brow = bt * 16 + r;
                short8v bb = *(short8v*)((char*)Bt + brow * 128 + (koff ^ ((brow & 7) << 4)));
                acc[bt] = __builtin_amdgcn_mfma_f32_16x16x32_bf16(a, bb, acc[bt], 0, 0, 0);
            }
        }
    }
    __syncthreads();
    float bias[4];
#pragma unroll
    for (int j = 0; j < 4; ++j) bias[j] = ob[v0 + wid * 16 + g * 4 + j];
#pragma unroll
    for (int bt = 0; bt < 4; ++bt)
#pragma unroll
        for (int j = 0; j < 4; ++j)
            Ct[bt * 16 + r][wid * 16 + g * 4 + j] = acc[bt][j] + bias[j];
    __syncthreads();
    int ob_ = t >> 2;
    int vq = (t & 3) * 16;
    float4 vals[4];
    float pm = -3.4e38f;
#pragma unroll
    for (int c = 0; c < 4; ++c) {
        vals[c] = *(float4*)&Ct[ob_][vq + c * 4];
        pm = fmaxf(pm, fmaxf(fmaxf(vals[c].x, vals[c].y), fmaxf(vals[c].z, vals[c].w)));
        *(float4*)(outl + (size_t)ob_ * V + v0 + vq + c * 4) = vals[c];
    }
    float ps = 0.f;
#pragma unroll
    for (int c = 0; c < 4; ++c)
        ps += expf(vals[c].x - pm) + expf(vals[c].y - pm) +
              expf(vals[c].z - pm) + expf(vals[c].w - pm);
#pragma unroll
    for (int x = 1; x <= 2; x <<= 1) {
        float om = __shfl_xor(pm, x);
        float os = __shfl_xor(ps, x);
        float nm = fmaxf(pm, om);
        ps = ps * expf(pm - nm) + os * expf(om - nm);
        pm = nm;
    }
    if ((t & 3) == 0) {
        lsp[((size_t)ob_ * NVT + blockIdx.x) * 2]     = pm;
        lsp[((size_t)ob_ * NVT + blockIdx.x) * 2 + 1] = ps;
    }
}

// ---------------- K6: merge lse partials + log_softmax subtract -------------
__global__ __launch_bounds__(256) void lsub_kernel(const float* __restrict__ lsp,
                                                   float* __restrict__ lg) {
    __shared__ float rm[256], rl[256];
    int blk = blockIdx.x;
    int b = blk >> 5, chunk = blk & 31;
    int t = threadIdx.x;
    const float* pb = lsp + (size_t)b * (NVT * 2);
    float m = pb[t * 2], l = pb[t * 2 + 1];
    int i2 = t + 256;
    if (i2 < NVT) {
        float m1 = pb[i2 * 2], l1 = pb[i2 * 2 + 1];
        float nm = fmaxf(m, m1);
        l = l * expf(m - nm) + l1 * expf(m1 - nm);
        m = nm;
    }
    rm[t] = m; rl[t] = l; __syncthreads();
    for (int s2 = 128; s2; s2 >>= 1) {
        if (t < s2) {
            float m2 = rm[t + s2], l2 = rl[t + s2];
            float nm = fmaxf(rm[t], m2);
            rl[t] = rl[t] * expf(rm[t] - nm) + l2 * expf(m2 - nm);
            rm[t] = nm;
        }
        __syncthreads();
    }
    float c = rm[0] + logf(rl[0]);
    if (t < 250) {
        float4* p = (float4*)(lg + (size_t)b * V + chunk * 1000) + t;
        float4 x = *p;
        x.x -= c; x.y -= c; x.z -= c; x.w -= c;
        *p = x;
    }
}

// ---------------- launch ----------------------------------------------------
extern "C" void kernel_launch(void* const* d_in, const int* in_sizes, int n_in,
                              void* d_out, int out_size, void* d_ws, size_t ws_size,
                              hipStream_t stream) {
    const int*   ib      = (const int*)d_in[0];
    const float* prev_h  = (const float*)d_in[1];
    const float* prev_c  = (const float*)d_in[2];
    const float* enc     = (const float*)d_in[3];
    const float* emb_W   = (const float*)d_in[4];
    const float* attn_W  = (const float*)d_in[5];
    const float* attn_b  = (const float*)d_in[6];
    const float* W_ih    = (const float*)d_in[7];
    const float* W_hh    = (const float*)d_in[8];
    const float* b_ih    = (const float*)d_in[9];
    const float* b_hh    = (const float*)d_in[10];
    const float* out_W   = (const float*)d_in[11];
    const float* out_b   = (const float*)d_in[12];

    float* ws = (float*)d_ws;
    float* sc   = ws;                        // 131072  scores (B*S)
    float* cp   = ws + 131072;               // 1048576 ctx partials [16][B][H]
    float* gp   = ws + 1179648;              // 2097152 gates partials [8][G4][B]
    float* mlc  = ws + 3276800;              // 2048
    ushort* xb  = (ushort*)(ws + 3278848);   // 163840 ushorts = bf16 x_cat [B][KC]
    ushort* hb  = (ushort*)(ws + 3360768);   // 65536 ushorts = bf16 hidden [B][H]
    float* lsp  = ws + 3393536;              // 64000 lse partials [B][NVT][2]

    float* out    = (float*)d_out;
    float* out_ls = out;                         // (B,V)
    float* out_h  = out + (size_t)B * V;         // (B,H)
    float* out_c  = out_h + (size_t)B * H;       // (B,H)
    float* out_a  = out_c + (size_t)B * H;       // (B,S)

    hipLaunchKernelGGL(fused_attn_kernel,  dim3(1024), dim3(256), 0, stream, enc, attn_W, attn_b, prev_h, sc, cp, mlc);
    hipLaunchKernelGGL(attn_reduce_kernel, dim3(256),  dim3(256), 0, stream, cp, mlc, sc, ib, emb_W, prev_h, xb, out_a);
    hipLaunchKernelGGL(gates_mfma,         dim3(512),  dim3(256), 0, stream, W_ih, W_hh, xb, gp);
    hipLaunchKernelGGL(lstm_kernel,        dim3(256),  dim3(256), 0, stream, gp, b_ih, b_hh, prev_c, out_h, out_c, hb);
    hipLaunchKernelGGL(logits_mfma,        dim3(NVT),  dim3(256), 0, stream, out_W, out_b, hb, out_ls, lsp);
    hipLaunchKernelGGL(lsub_kernel,        dim3(2048), dim3(256), 0, stream, lsp, out_ls);
}

// Round 9
// 168.350 us; speedup vs baseline: 1.0289x; 1.0289x over previous
//
#include <hip/hip_runtime.h>
#include <math.h>

// Problem constants
#define B 64
#define S 2048
#define H 1024
#define E 512
#define V 32000
#define G4 4096        // 4*H
#define KX 1536        // E+H
#define KC 2560        // E+H+H
#define NVT 500        // number of v-tiles in logits GEMM (V/64)

typedef __attribute__((ext_vector_type(8))) short short8v;
typedef __attribute__((ext_vector_type(4))) float f32x4;

__device__ __forceinline__ ushort f2bf(float f) {
    union { float f; unsigned u; } v; v.f = f;
    unsigned r = v.u + 0x7FFFu + ((v.u >> 16) & 1u);
    return (ushort)(r >> 16);
}

__device__ __forceinline__ float4 ntload4(const float* p) {
    f32x4 v = __builtin_nontemporal_load((const f32x4*)p);
    return make_float4(v[0], v[1], v[2], v[3]);
}

// ---------------- K1: fused flash attention over enc (single enc pass) ------
// 1024 blocks: b = blk>>4, cpair = blk&15 -> s-chunks {2*cpair, 2*cpair+1}.
// hwh computed inline per block. __launch_bounds__(256,4): 4 waves/EU ->
// 4 blocks/CU -> all 1024 blocks co-resident (no tail round); VGPR <= 128.
__global__ __launch_bounds__(256, 4) void fused_attn_kernel(const float* __restrict__ enc,
                                                            const float* __restrict__ attn_W,
                                                            const float* __restrict__ attn_b,
                                                            const float* __restrict__ prev_h,
                                                            float* __restrict__ scores,
                                                            float* __restrict__ cpart,
                                                            float* __restrict__ mlc) {
    __shared__ float red[256];
    __shared__ float mw[4], lw[4];
    __shared__ float cbuf[4][1024];
    int t = threadIdx.x;
    int lane = t & 63, wid = t >> 6;
    int b = blockIdx.x >> 4, cpair = blockIdx.x & 15;

    // inline hwh[b] = dot(prev_h[b,:], attn_W[0:H])
    {
        float4 p = *(const float4*)(prev_h + b * H + t * 4);
        float4 w = *(const float4*)(attn_W + t * 4);
        red[t] = p.x * w.x + p.y * w.y + p.z * w.z + p.w * w.w;
        __syncthreads();
        for (int s2 = 128; s2; s2 >>= 1) {
            if (t < s2) red[t] += red[t + s2];
            __syncthreads();
        }
    }
    float cst = red[0] + attn_b[0];

    const float* We = attn_W + H;
    float4 we4[4];
#pragma unroll
    for (int c = 0; c < 4; ++c) we4[c] = *(const float4*)(We + c * 256 + lane * 4);

    float m = -INFINITY, l = 0.f;
    float4 ctx4[4] = {{0,0,0,0},{0,0,0,0},{0,0,0,0},{0,0,0,0}};

    for (int cc = 0; cc < 2; ++cc) {
        int chunk = cpair * 2 + cc;
        int s0 = chunk * 64 + wid * 16;
        const float* rowp = enc + (size_t)s0 * (B * H) + b * H + lane * 4;
        float4 e4[4];
#pragma unroll
        for (int c = 0; c < 4; ++c) e4[c] = ntload4(rowp + c * 256);

        for (int i = 0; i < 16; ++i) {
            float4 cur[4];
#pragma unroll
            for (int c = 0; c < 4; ++c) cur[c] = e4[c];
            if (i < 15) {
                const float* np = rowp + (size_t)(i + 1) * (B * H);
#pragma unroll
                for (int c = 0; c < 4; ++c) e4[c] = ntload4(np + c * 256);
            }
            float acc = 0.f;
#pragma unroll
            for (int c = 0; c < 4; ++c)
                acc += cur[c].x * we4[c].x + cur[c].y * we4[c].y +
                       cur[c].z * we4[c].z + cur[c].w * we4[c].w;
#pragma unroll
            for (int x = 32; x; x >>= 1) acc += __shfl_xor(acc, x);
            float score = acc + cst;
            if (lane == 0) scores[b * S + s0 + i] = score;
            float nm = fmaxf(m, score);
            float sc = expf(m - nm);
            float w = expf(score - nm);
            l = l * sc + w;
            m = nm;
#pragma unroll
            for (int c = 0; c < 4; ++c) {
                ctx4[c].x = ctx4[c].x * sc + w * cur[c].x;
                ctx4[c].y = ctx4[c].y * sc + w * cur[c].y;
                ctx4[c].z = ctx4[c].z * sc + w * cur[c].z;
                ctx4[c].w = ctx4[c].w * sc + w * cur[c].w;
            }
        }
    }

    if (lane == 0) { mw[wid] = m; lw[wid] = l; }
    __syncthreads();
    float M = fmaxf(fmaxf(mw[0], mw[1]), fmaxf(mw[2], mw[3]));
    float L = lw[0] * expf(mw[0] - M) + lw[1] * expf(mw[1] - M) +
              lw[2] * expf(mw[2] - M) + lw[3] * expf(mw[3] - M);
    float msc = expf(m - M);
#pragma unroll
    for (int c = 0; c < 4; ++c) {
        float4 v = ctx4[c];
        v.x *= msc; v.y *= msc; v.z *= msc; v.w *= msc;
        *(float4*)&cbuf[wid][c * 256 + lane * 4] = v;
    }
    __syncthreads();
    if (wid == 0) {
#pragma unroll
        for (int c = 0; c < 4; ++c) {
            int h = c * 256 + lane * 4;
            float4 a0 = *(float4*)&cbuf[0][h];
            float4 a1 = *(float4*)&cbuf[1][h];
            float4 a2 = *(float4*)&cbuf[2][h];
            float4 a3 = *(float4*)&cbuf[3][h];
            float4 s4 = make_float4(a0.x + a1.x + a2.x + a3.x,
                                    a0.y + a1.y + a2.y + a3.y,
                                    a0.z + a1.z + a2.z + a3.z,
                                    a0.w + a1.w + a2.w + a3.w);
            *(float4*)(cpart + (size_t)(cpair * B + b) * H + h) = s4;
        }
    }
    if (t == 0) {
        mlc[(b * 16 + cpair) * 2] = M;
        mlc[(b * 16 + cpair) * 2 + 1] = L;
    }
}

// ---------------- K2: merge partials -> xb(bf16) context + weights + fill ---
// 256 blocks: b = blk>>2, quarter q = blk&3
__global__ __launch_bounds__(256) void attn_reduce_kernel(const float* __restrict__ cpart,
                                                          const float* __restrict__ mlc,
                                                          const float* __restrict__ scores,
                                                          const int* __restrict__ ib,
                                                          const float* __restrict__ emb_W,
                                                          const float* __restrict__ prev_h,
                                                          ushort* __restrict__ xb,
                                                          float* __restrict__ attn) {
    __shared__ float Ms[16], Ls[16], Es[16];
    int blk = blockIdx.x;
    int b = blk >> 2, q = blk & 3;
    int t = threadIdx.x;
    if (t < 16) {
        Ms[t] = mlc[(b * 16 + t) * 2];
        Ls[t] = mlc[(b * 16 + t) * 2 + 1];
    }
    __syncthreads();
    float Mg = -INFINITY;
#pragma unroll
    for (int c = 0; c < 16; ++c) Mg = fmaxf(Mg, Ms[c]);
    if (t < 16) Es[t] = expf(Ms[t] - Mg);
    __syncthreads();
    float Lg = 0.f;
#pragma unroll
    for (int c = 0; c < 16; ++c) Lg += Ls[c] * Es[c];
    float inv = 1.f / Lg;
    // context quarter
    int h = q * 256 + t;
    float acc = 0.f;
#pragma unroll 4
    for (int c = 0; c < 16; ++c)
        acc += Es[c] * cpart[(size_t)(c * B + b) * H + h];
    xb[(size_t)b * KC + E + h] = f2bf(acc * inv);
    // attn weights: s in [q*512, q*512+512)
#pragma unroll
    for (int i = 0; i < 2; ++i) {
        int s = q * 512 + i * 256 + t;
        attn[b * S + s] = expf(scores[b * S + s] - Mg) * inv;
    }
    // xb fill (emb + prev_h): j range [q*384, q*384+384)
#pragma unroll
    for (int i = 0; i < 2; ++i) {
        int j = q * 384 + i * 256 + t;
        if (i == 1 && t >= 128) break;
        if (j < E) xb[(size_t)b * KC + j] = f2bf(emb_W[(size_t)ib[b] * E + j]);
        else       xb[(size_t)b * KC + KX + (j - E)] = f2bf(prev_h[b * H + (j - E)]);
    }
}

// ---------------- K3: gates GEMM via bf16 MFMA ------------------------------
// gpart[ks][r][b] = sum_{k in 320-chunk ks} W[r,k]*x[b,k]. 512 blocks.
__global__ __launch_bounds__(256) void gates_mfma(const float* __restrict__ W_ih,
                                                  const float* __restrict__ W_hh,
                                                  const ushort* __restrict__ xb,
                                                  float* __restrict__ gpart) {
    __shared__ ushort Wt[64 * 64];   // [r][k] bf16, swizzled
    __shared__ ushort Bt[64 * 64];   // [b][k] bf16, swizzled
    int t = threadIdx.x;
    int lane = t & 63, wid = t >> 6;
    int rtile = blockIdx.x >> 3, ks = blockIdx.x & 7;
    int r0 = rtile * 64;

    int srow = t >> 2;
    int sq = t & 3;

    f32x4 acc[4] = {{0.f,0.f,0.f,0.f},{0.f,0.f,0.f,0.f},{0.f,0.f,0.f,0.f},{0.f,0.f,0.f,0.f}};

    int r = lane & 15, g = lane >> 4;
    int arow = wid * 16 + r;
    int aswz = (arow & 7) << 4;
    unsigned abase = arow * 128;

    for (int kt = 0; kt < 5; ++kt) {
        int kb = ks * 320 + kt * 64;
        const float* wbase;
        int wstride;
        if (kb < KX) { wbase = W_ih + kb; wstride = KX; }
        else         { wbase = W_hh + (kb - KX); wstride = H; }
        __syncthreads();
        {
            const float* src = wbase + (size_t)(r0 + srow) * wstride + sq * 16;
            float4 f0 = ntload4(src + 0);
            float4 f1 = ntload4(src + 4);
            float4 f2 = ntload4(src + 8);
            float4 f3 = ntload4(src + 12);
            short8v w0, w1;
            w0[0] = (short)f2bf(f0.x); w0[1] = (short)f2bf(f0.y);
            w0[2] = (short)f2bf(f0.z); w0[3] = (short)f2bf(f0.w);
            w0[4] = (short)f2bf(f1.x); w0[5] = (short)f2bf(f1.y);
            w0[6] = (short)f2bf(f1.z); w0[7] = (short)f2bf(f1.w);
            w1[0] = (short)f2bf(f2.x); w1[1] = (short)f2bf(f2.y);
            w1[2] = (short)f2bf(f2.z); w1[3] = (short)f2bf(f2.w);
            w1[4] = (short)f2bf(f3.x); w1[5] = (short)f2bf(f3.y);
            w1[6] = (short)f2bf(f3.z); w1[7] = (short)f2bf(f3.w);
            unsigned rb = srow * 128;
            unsigned sw = (srow & 7) << 4;
            *(short8v*)((char*)Wt + rb + ((sq * 32 + 0) ^ sw))  = w0;
            *(short8v*)((char*)Wt + rb + ((sq * 32 + 16) ^ sw)) = w1;
        }
        {
            const ushort* hsrc = xb + (size_t)srow * KC + kb + sq * 16;
            uint4 h0 = *(const uint4*)(hsrc);
            uint4 h1 = *(const uint4*)(hsrc + 8);
            unsigned rb = srow * 128;
            unsigned sw = (srow & 7) << 4;
            *(uint4*)((char*)Bt + rb + ((sq * 32 + 0) ^ sw))  = h0;
            *(uint4*)((char*)Bt + rb + ((sq * 32 + 16) ^ sw)) = h1;
        }
        __syncthreads();
#pragma unroll
        for (int kk = 0; kk < 2; ++kk) {
            unsigned koff = kk * 64 + g * 16;
            short8v a = *(short8v*)((char*)Wt + abase + (koff ^ aswz));
#pragma unroll
            for (int bt = 0; bt < 4; ++bt) {
                int brow = bt * 16 + r;
                short8v bb = *(short8v*)((char*)Bt + brow * 128 + (koff ^ ((brow & 7) << 4)));
                acc[bt] = __builtin_amdgcn_mfma_f32_16x16x32_bf16(a, bb, acc[bt], 0, 0, 0);
            }
        }
    }
    // direct scatter store: r_global = r0 + wid*16 + g*4 + j; b = bt*16 + r
#pragma unroll
    for (int bt = 0; bt < 4; ++bt) {
        int bcol = bt * 16 + r;
#pragma unroll
        for (int j = 0; j < 4; ++j) {
            int rg = r0 + wid * 16 + g * 4 + j;
            gpart[(size_t)ks * (G4 * B) + (size_t)rg * B + bcol] = acc[bt][j];
        }
    }
}

// ---------------- K4: LSTM elementwise (8 partials, emits bf16 hb[b][k]) ----
__global__ __launch_bounds__(256) void lstm_kernel(const float* __restrict__ gpart,
                                                   const float* __restrict__ b_ih,
                                                   const float* __restrict__ b_hh,
                                                   const float* __restrict__ prev_c,
                                                   float* __restrict__ hidden_out,
                                                   float* __restrict__ cell_out,
                                                   ushort* __restrict__ hb) {
    int t = blockIdx.x * 256 + threadIdx.x;  // 65536
    int b = t & 63, h = t >> 6;
    float g[4];
#pragma unroll
    for (int q = 0; q < 4; ++q) {
        int r = h + q * H;
        float a = b_ih[r] + b_hh[r];
#pragma unroll
        for (int ks = 0; ks < 8; ++ks) a += gpart[(size_t)ks * (G4 * B) + r * B + b];
        g[q] = a;
    }
    float ig = 1.f / (1.f + expf(-g[0]));
    float fg = 1.f / (1.f + expf(-g[1]));
    float gg = tanhf(g[2]);
    float og = 1.f / (1.f + expf(-g[3]));
    float c = fg * prev_c[b * H + h] + ig * gg;
    float hd = og * tanhf(c);
    cell_out[b * H + h] = c;
    hidden_out[b * H + h] = hd;
    hb[b * H + h] = f2bf(hd);
}

// ---------------- K5: logits via bf16 MFMA + inline partial logsumexp -------
__global__ __launch_bounds__(256) void logits_mfma(const float* __restrict__ W,
                                                   const float* __restrict__ ob,
                                                   const ushort* __restrict__ hb,
                                                   float* __restrict__ outl,
                                                   float* __restrict__ lsp) {
    __shared__ ushort Wt[64 * 64];   // [v][k] bf16, swizzled
    __shared__ ushort Bt[64 * 64];   // [b][k] bf16, swizzled
    __shared__ float  Ct[64][68];    // [b][v] transpose buffer
    int t = threadIdx.x;
    int lane = t & 63, wid = t >> 6;
    int v0 = blockIdx.x * 64;

    int srow = t >> 2;
    int sq = t & 3;

    f32x4 acc[4] = {{0.f,0.f,0.f,0.f},{0.f,0.f,0.f,0.f},{0.f,0.f,0.f,0.f},{0.f,0.f,0.f,0.f}};

    int r = lane & 15, g = lane >> 4;
    int arow = wid * 16 + r;
    int aswz = (arow & 7) << 4;
    unsigned abase = arow * 128;

    for (int kt = 0; kt < 16; ++kt) {
        int k0 = kt * 64;
        __syncthreads();
        {
            const float* src = W + (size_t)(v0 + srow) * H + k0 + sq * 16;
            float4 f0 = ntload4(src + 0);
            float4 f1 = ntload4(src + 4);
            float4 f2 = ntload4(src + 8);
            float4 f3 = ntload4(src + 12);
            short8v w0, w1;
            w0[0] = (short)f2bf(f0.x); w0[1] = (short)f2bf(f0.y);
            w0[2] = (short)f2bf(f0.z); w0[3] = (short)f2bf(f0.w);
            w0[4] = (short)f2bf(f1.x); w0[5] = (short)f2bf(f1.y);
            w0[6] = (short)f2bf(f1.z); w0[7] = (short)f2bf(f1.w);
            w1[0] = (short)f2bf(f2.x); w1[1] = (short)f2bf(f2.y);
            w1[2] = (short)f2bf(f2.z); w1[3] = (short)f2bf(f2.w);
            w1[4] = (short)f2bf(f3.x); w1[5] = (short)f2bf(f3.y);
            w1[6] = (short)f2bf(f3.z); w1[7] = (short)f2bf(f3.w);
            unsigned rb = srow * 128;
            unsigned sw = (srow & 7) << 4;
            *(short8v*)((char*)Wt + rb + ((sq * 32 + 0) ^ sw))  = w0;
            *(short8v*)((char*)Wt + rb + ((sq * 32 + 16) ^ sw)) = w1;
        }
        {
            const ushort* hsrc = hb + (size_t)srow * H + k0 + sq * 16;
            uint4 h0 = *(const uint4*)(hsrc);
            uint4 h1 = *(const uint4*)(hsrc + 8);
            unsigned rb = srow * 128;
            unsigned sw = (srow & 7) << 4;
            *(uint4*)((char*)Bt + rb + ((sq * 32 + 0) ^ sw))  = h0;
            *(uint4*)((char*)Bt + rb + ((sq * 32 + 16) ^ sw)) = h1;
        }
        __syncthreads();
#pragma unroll
        for (int kk = 0; kk < 2; ++kk) {
            unsigned koff = kk * 64 + g * 16;
            short8v a = *(short8v*)((char*)Wt + abase + (koff ^ aswz));
#pragma unroll
            for (int bt = 0; bt < 4; ++bt) {
                int brow = bt * 16 + r;
                short8v bb = *(short8v*)((char*)Bt + brow * 128 + (koff ^ ((brow & 7) << 4)));
                acc[bt] = __builtin_amdgcn_mfma_f32_16x16x32_bf16(a, bb, acc[bt], 0, 0, 0);
            }
        }
    }
    __syncthreads();
    float bias[4];
#pragma unroll
    for (int j = 0; j < 4; ++j) bias[j] = ob[v0 + wid * 16 + g * 4 + j];
#pragma unroll
    for (int bt = 0; bt < 4; ++bt)
#pragma unroll
        for (int j = 0; j < 4; ++j)
            Ct[bt * 16 + r][wid * 16 + g * 4 + j] = acc[bt][j] + bias[j];
    __syncthreads();
    int ob_ = t >> 2;
    int vq = (t & 3) * 16;
    float4 vals[4];
    float pm = -3.4e38f;
#pragma unroll
    for (int c = 0; c < 4; ++c) {
        vals[c] = *(float4*)&Ct[ob_][vq + c * 4];
        pm = fmaxf(pm, fmaxf(fmaxf(vals[c].x, vals[c].y), fmaxf(vals[c].z, vals[c].w)));
        *(float4*)(outl + (size_t)ob_ * V + v0 + vq + c * 4) = vals[c];
    }
    float ps = 0.f;
#pragma unroll
    for (int c = 0; c < 4; ++c)
        ps += expf(vals[c].x - pm) + expf(vals[c].y - pm) +
              expf(vals[c].z - pm) + expf(vals[c].w - pm);
#pragma unroll
    for (int x = 1; x <= 2; x <<= 1) {
        float om = __shfl_xor(pm, x);
        float os = __shfl_xor(ps, x);
        float nm = fmaxf(pm, om);
        ps = ps * expf(pm - nm) + os * expf(om - nm);
        pm = nm;
    }
    if ((t & 3) == 0) {
        lsp[((size_t)ob_ * NVT + blockIdx.x) * 2]     = pm;
        lsp[((size_t)ob_ * NVT + blockIdx.x) * 2 + 1] = ps;
    }
}

// ---------------- K6: merge lse partials + log_softmax subtract -------------
__global__ __launch_bounds__(256) void lsub_kernel(const float* __restrict__ lsp,
                                                   float* __restrict__ lg) {
    __shared__ float rm[256], rl[256];
    int blk = blockIdx.x;
    int b = blk >> 5, chunk = blk & 31;
    int t = threadIdx.x;
    const float* pb = lsp + (size_t)b * (NVT * 2);
    float m = pb[t * 2], l = pb[t * 2 + 1];
    int i2 = t + 256;
    if (i2 < NVT) {
        float m1 = pb[i2 * 2], l1 = pb[i2 * 2 + 1];
        float nm = fmaxf(m, m1);
        l = l * expf(m - nm) + l1 * expf(m1 - nm);
        m = nm;
    }
    rm[t] = m; rl[t] = l; __syncthreads();
    for (int s2 = 128; s2; s2 >>= 1) {
        if (t < s2) {
            float m2 = rm[t + s2], l2 = rl[t + s2];
            float nm = fmaxf(rm[t], m2);
            rl[t] = rl[t] * expf(rm[t] - nm) + l2 * expf(m2 - nm);
            rm[t] = nm;
        }
        __syncthreads();
    }
    float c = rm[0] + logf(rl[0]);
    if (t < 250) {
        float4* p = (float4*)(lg + (size_t)b * V + chunk * 1000) + t;
        float4 x = *p;
        x.x -= c; x.y -= c; x.z -= c; x.w -= c;
        *p = x;
    }
}

// ---------------- launch ----------------------------------------------------
extern "C" void kernel_launch(void* const* d_in, const int* in_sizes, int n_in,
                              void* d_out, int out_size, void* d_ws, size_t ws_size,
                              hipStream_t stream) {
    const int*   ib      = (const int*)d_in[0];
    const float* prev_h  = (const float*)d_in[1];
    const float* prev_c  = (const float*)d_in[2];
    const float* enc     = (const float*)d_in[3];
    const float* emb_W   = (const float*)d_in[4];
    const float* attn_W  = (const float*)d_in[5];
    const float* attn_b  = (const float*)d_in[6];
    const float* W_ih    = (const float*)d_in[7];
    const float* W_hh    = (const float*)d_in[8];
    const float* b_ih    = (const float*)d_in[9];
    const float* b_hh    = (const float*)d_in[10];
    const float* out_W   = (const float*)d_in[11];
    const float* out_b   = (const float*)d_in[12];

    float* ws = (float*)d_ws;
    // ws layout (floats), total ~13.8 MB
    float* sc   = ws;                        // 131072  scores (B*S)
    float* cp   = ws + 131072;               // 1048576 ctx partials [16][B][H]
    float* gp   = ws + 1179648;              // 2097152 gates partials [8][G4][B]
    float* mlc  = ws + 3276800;              // 2048
    ushort* xb  = (ushort*)(ws + 3278848);   // 163840 ushorts = bf16 x_cat [B][KC]
    ushort* hb  = (ushort*)(ws + 3360768);   // 65536 ushorts = bf16 hidden [B][H]
    float* lsp  = ws + 3393536;              // 64000 lse partials [B][NVT][2]

    float* out    = (float*)d_out;
    float* out_ls = out;                         // (B,V)
    float* out_h  = out + (size_t)B * V;         // (B,H)
    float* out_c  = out_h + (size_t)B * H;       // (B,H)
    float* out_a  = out_c + (size_t)B * H;       // (B,S)

    hipLaunchKernelGGL(fused_attn_kernel,  dim3(1024), dim3(256), 0, stream, enc, attn_W, attn_b, prev_h, sc, cp, mlc);
    hipLaunchKernelGGL(attn_reduce_kernel, dim3(256),  dim3(256), 0, stream, cp, mlc, sc, ib, emb_W, prev_h, xb, out_a);
    hipLaunchKernelGGL(gates_mfma,         dim3(512),  dim3(256), 0, stream, W_ih, W_hh, xb, gp);
    hipLaunchKernelGGL(lstm_kernel,        dim3(256),  dim3(256), 0, stream, gp, b_ih, b_hh, prev_c, out_h, out_c, hb);
    hipLaunchKernelGGL(logits_mfma,        dim3(NVT),  dim3(256), 0, stream, out_W, out_b, hb, out_ls, lsp);
    hipLaunchKernelGGL(lsub_kernel,        dim3(2048), dim3(256), 0, stream, lsp, out_ls);
}